// Round 1
// baseline (810.814 us; speedup 1.0000x reference)
//
#include <hip/hip_runtime.h>
#include <hip/hip_bf16.h>

// Problem constants
#define N_PTS   100000
#define P_CELLS 409600          // 640*640
#define D_DIM   64
#define OUT_ELEMS (4u * 64u * 409600u)   // 104,857,600 floats = 419 MB

// ---------------------------------------------------------------------------
// Kernel 1: zero the output (harness poisons d_out with 0xAA before every
// timed launch, and the scatter phase needs zeroed accumulators).
// ---------------------------------------------------------------------------
__global__ void zero_out_kernel(float4* __restrict__ out, unsigned n4) {
    unsigned i = blockIdx.x * blockDim.x + threadIdx.x;
    unsigned stride = gridDim.x * blockDim.x;
    const float4 z = make_float4(0.f, 0.f, 0.f, 0.f);
    for (; i < n4; i += stride) out[i] = z;
}

// ---------------------------------------------------------------------------
// Kernel 2: one wave per point. lane = feature index d (0..63).
//   emb[d] = relu((dot(pc, W[d]) + b[d]) * scale[d] + shift[d]) * mask
//   scale = gamma * rsqrt(var + eps); shift = beta - mean*scale
// Scatter-add into out[((b*2+t)*64 + d) * P + p].
// ---------------------------------------------------------------------------
__global__ void scatter_kernel(
    const float* __restrict__ prev_pcl, const int* __restrict__ prev_mask,
    const int*   __restrict__ prev_grid,
    const float* __restrict__ cur_pcl,  const int* __restrict__ cur_mask,
    const int*   __restrict__ cur_grid,
    const float* __restrict__ W,     const float* __restrict__ bvec,
    const float* __restrict__ gamma, const float* __restrict__ beta,
    const float* __restrict__ mean,  const float* __restrict__ var,
    float* __restrict__ out)
{
    const int lane = threadIdx.x & 63;

    // Per-lane (= per-feature d) constants, hoisted out of the point loop.
    const float w0 = W[lane * 3 + 0];
    const float w1 = W[lane * 3 + 1];
    const float w2 = W[lane * 3 + 2];
    const float scale = gamma[lane] * rsqrtf(var[lane] + 1e-5f);
    const float shift = beta[lane] - mean[lane] * scale;
    const float bias  = bvec[lane];

    const unsigned wave   = (blockIdx.x * blockDim.x + threadIdx.x) >> 6;
    const unsigned nwaves = (gridDim.x * blockDim.x) >> 6;
    const unsigned total  = 2u * 2u * N_PTS;   // 400000 point-tasks

    for (unsigned task = wave; task < total; task += nwaves) {
        const unsigned t = task / (2u * N_PTS);          // 0 = prev, 1 = cur
        const unsigned r = task - t * 2u * N_PTS;
        const unsigned b = r / N_PTS;                    // batch
        const unsigned n = r - b * N_PTS;                // point index

        const float* pcl = t ? cur_pcl  : prev_pcl;
        const int*   msk = t ? cur_mask : prev_mask;
        const int*   grd = t ? cur_grid : prev_grid;

        const int m = msk[b * N_PTS + n];                // wave-uniform branch
        if (!m) continue;

        const unsigned p = (unsigned)grd[b * N_PTS + n];
        const float x = pcl[(size_t)(b * N_PTS + n) * 3 + 0];
        const float y = pcl[(size_t)(b * N_PTS + n) * 3 + 1];
        const float z = pcl[(size_t)(b * N_PTS + n) * 3 + 2];

        float h = fmaf(x, w0, fmaf(y, w1, fmaf(z, w2, bias)));
        h = fmaf(h, scale, shift);
        h = fmaxf(h, 0.f);

        const unsigned c = b * 2u + t;                   // output cloud index
        if (h > 0.f) {
            unsafeAtomicAdd(out + (size_t)(c * 64u + lane) * P_CELLS + p, h);
        }
    }
}

// ---------------------------------------------------------------------------
extern "C" void kernel_launch(void* const* d_in, const int* in_sizes, int n_in,
                              void* d_out, int out_size, void* d_ws, size_t ws_size,
                              hipStream_t stream) {
    const float* prev_pcl  = (const float*)d_in[0];
    const int*   prev_mask = (const int*)  d_in[1];
    const int*   prev_grid = (const int*)  d_in[2];
    const float* cur_pcl   = (const float*)d_in[3];
    const int*   cur_mask  = (const int*)  d_in[4];
    const int*   cur_grid  = (const int*)  d_in[5];
    const float* W     = (const float*)d_in[6];
    const float* bvec  = (const float*)d_in[7];
    const float* gam   = (const float*)d_in[8];
    const float* bet   = (const float*)d_in[9];
    const float* mean  = (const float*)d_in[10];
    const float* var   = (const float*)d_in[11];
    float* out = (float*)d_out;

    // Phase 1: zero 419 MB of output.
    zero_out_kernel<<<2048, 256, 0, stream>>>((float4*)out, OUT_ELEMS / 4);

    // Phase 2: embed + atomic scatter. 2048 blocks x 256 = 8192 waves,
    // ~49 points per wave.
    scatter_kernel<<<2048, 256, 0, stream>>>(
        prev_pcl, prev_mask, prev_grid,
        cur_pcl,  cur_mask,  cur_grid,
        W, bvec, gam, bet, mean, var, out);
}

// Round 2
// 499.218 us; speedup vs baseline: 1.6242x; 1.6242x over previous
//
#include <hip/hip_runtime.h>

// Problem constants
#define N_PTS   100000
#define P_CELLS 409600          // 640*640
#define NCLOUD  4               // B=2 batches x {prev, cur}; cloud c = b*2 + t

// ---------------------------------------------------------------------------
// Kernel 1: build per-cell linked lists of masked points.
//   head[c*P + p] -> most recent point gid, next[gid] -> previous, -1 ends.
//   gid encodes (c, n): gid = c*N_PTS + n;  t = c&1 selects prev/cur arrays,
//   b = c>>1 is the batch.
// head is memset to 0xFF (== -1) by kernel_launch before this runs.
// ---------------------------------------------------------------------------
__global__ void build_lists(
    const int* __restrict__ prev_mask, const int* __restrict__ prev_grid,
    const int* __restrict__ cur_mask,  const int* __restrict__ cur_grid,
    int* __restrict__ head, int* __restrict__ next)
{
    int gid = blockIdx.x * blockDim.x + threadIdx.x;
    if (gid >= NCLOUD * N_PTS) return;
    int c = gid / N_PTS;
    int n = gid - c * N_PTS;
    int t = c & 1;
    int b = c >> 1;
    const int* msk = t ? cur_mask : prev_mask;
    const int* grd = t ? cur_grid : prev_grid;
    int e = b * N_PTS + n;
    if (!msk[e]) return;
    int p = grd[e];
    int old = atomicExch(&head[c * P_CELLS + p], gid);
    next[gid] = old;
}

// ---------------------------------------------------------------------------
// Kernel 2: gather. One thread per (cloud c, cell p). Chases the cell's
// chain (avg 0.12 points), accumulates 64 ReLU'd features, then writes all
// 64 output dwords (stride P apart per-thread; consecutive lanes cover
// consecutive p, so each wave store instruction is a dense 256 B write).
// Every output element is written exactly once: no zero pass, no atomics.
// ---------------------------------------------------------------------------
__global__ __launch_bounds__(256) void gather_kernel(
    const int* __restrict__ head, const int* __restrict__ next,
    const float* __restrict__ prev_pcl, const float* __restrict__ cur_pcl,
    const float* __restrict__ W,     const float* __restrict__ bvec,
    const float* __restrict__ gamma, const float* __restrict__ beta,
    const float* __restrict__ mean,  const float* __restrict__ var,
    float* __restrict__ out)
{
    // Fused per-feature constants in LDS (broadcast reads, conflict-free):
    //   h_d = relu( x*W0'[d] + y*W1'[d] + z*W2'[d] + C[d] )
    //   W*' = W* * s,  C = (b - mean)*s + beta,  s = gamma*rsqrt(var+eps)
    __shared__ float w0s[64], w1s[64], w2s[64], cs[64];
    const int tid = threadIdx.x;
    if (tid < 64) {
        float s = gamma[tid] * rsqrtf(var[tid] + 1e-5f);
        w0s[tid] = W[tid * 3 + 0] * s;
        w1s[tid] = W[tid * 3 + 1] * s;
        w2s[tid] = W[tid * 3 + 2] * s;
        cs[tid]  = (bvec[tid] - mean[tid]) * s + beta[tid];
    }
    __syncthreads();

    const int c = blockIdx.y;                          // cloud 0..3
    const int p = blockIdx.x * blockDim.x + tid;       // cell 0..P-1

    const float* pcl  = (c & 1) ? cur_pcl : prev_pcl;  // t = c&1
    const int    base = (c >> 1) * N_PTS;              // batch offset
    const int    cbase = c * N_PTS;                    // gid base for this cloud

    float acc[64];
#pragma unroll
    for (int d = 0; d < 64; ++d) acc[d] = 0.f;

    int idx = head[c * P_CELLS + p];
    while (idx >= 0) {                  // wave skips entirely if all lanes empty
        int nxt = next[idx];            // issue chase load before compute
        int n = idx - cbase;
        const float* q = pcl + (size_t)(base + n) * 3;
        float x = q[0], y = q[1], z = q[2];
#pragma unroll
        for (int d = 0; d < 64; ++d) {
            float v = fmaf(x, w0s[d], fmaf(y, w1s[d], fmaf(z, w2s[d], cs[d])));
            acc[d] += fmaxf(v, 0.f);
        }
        idx = nxt;
    }

    float* op = out + (size_t)c * 64u * P_CELLS + p;
#pragma unroll
    for (int d = 0; d < 64; ++d)
        op[(size_t)d * P_CELLS] = acc[d];
}

// ---------------------------------------------------------------------------
extern "C" void kernel_launch(void* const* d_in, const int* in_sizes, int n_in,
                              void* d_out, int out_size, void* d_ws, size_t ws_size,
                              hipStream_t stream) {
    const float* prev_pcl  = (const float*)d_in[0];
    const int*   prev_mask = (const int*)  d_in[1];
    const int*   prev_grid = (const int*)  d_in[2];
    const float* cur_pcl   = (const float*)d_in[3];
    const int*   cur_mask  = (const int*)  d_in[4];
    const int*   cur_grid  = (const int*)  d_in[5];
    const float* W     = (const float*)d_in[6];
    const float* bvec  = (const float*)d_in[7];
    const float* gam   = (const float*)d_in[8];
    const float* bet   = (const float*)d_in[9];
    const float* mean  = (const float*)d_in[10];
    const float* var   = (const float*)d_in[11];
    float* out = (float*)d_out;

    // Workspace layout: head[4*P] ints, then next[4*N] ints  (~8.2 MB).
    int* head = (int*)d_ws;
    int* next = head + NCLOUD * P_CELLS;

    // head = -1 everywhere (ws is poisoned each call).
    hipMemsetAsync(head, 0xFF, (size_t)NCLOUD * P_CELLS * sizeof(int), stream);

    // Build per-cell chains: 400k point-tasks.
    build_lists<<<(NCLOUD * N_PTS + 255) / 256, 256, 0, stream>>>(
        prev_mask, prev_grid, cur_mask, cur_grid, head, next);

    // Gather: 4 clouds x 409600 cells, one thread each.
    dim3 ggrid(P_CELLS / 256, NCLOUD);
    gather_kernel<<<ggrid, 256, 0, stream>>>(
        head, next, prev_pcl, cur_pcl,
        W, bvec, gam, bet, mean, var, out);
}

// Round 3
// 459.418 us; speedup vs baseline: 1.7649x; 1.0866x over previous
//
#include <hip/hip_runtime.h>

// Problem constants
#define N_PTS   100000
#define P_CELLS 409600          // 640*640
#define NCLOUD  4               // B=2 batches x {prev, cur}; cloud c = b*2 + t

// Workspace layout (ws is ~GB, we use ~13 MB):
//   [0)      k0[64],k1[64],k2[64],k3[64]  fused constants (1 KB)
//   [1024)   head[4*P] ints               (6.55 MB)
//   [+...]   node[4*N] float4             (6.4 MB)  {x,y,z,next-as-bits}
#define WS_CONST_FLOATS 256
#define WS_HEAD_OFF     1024

// ---------------------------------------------------------------------------
// Kernel 0: fuse Linear+BN constants. 64 threads.
//   h_d = relu(x*k0[d] + y*k1[d] + z*k2[d] + k3[d])
//   k* = W*[d]*s,  k3 = (b[d]-mean[d])*s + beta[d],  s = gamma*rsqrt(var+eps)
// ---------------------------------------------------------------------------
__global__ void make_consts(
    const float* __restrict__ W,     const float* __restrict__ bvec,
    const float* __restrict__ gamma, const float* __restrict__ beta,
    const float* __restrict__ mean,  const float* __restrict__ var,
    float* __restrict__ k)
{
    int d = threadIdx.x;
    if (d >= 64) return;
    float s = gamma[d] * rsqrtf(var[d] + 1e-5f);
    k[d]       = W[d * 3 + 0] * s;
    k[64 + d]  = W[d * 3 + 1] * s;
    k[128 + d] = W[d * 3 + 2] * s;
    k[192 + d] = (bvec[d] - mean[d]) * s + beta[d];
}

// ---------------------------------------------------------------------------
// Kernel 1: build per-cell linked lists of masked points with fat nodes.
//   head[c*P + p] -> most recent gid, node[gid].w -> prev gid bits, -1 ends.
//   node[gid] = {x, y, z, next}: one 16 B load per chain hop in gather.
// ---------------------------------------------------------------------------
__global__ void build_lists(
    const float* __restrict__ prev_pcl, const int* __restrict__ prev_mask,
    const int*   __restrict__ prev_grid,
    const float* __restrict__ cur_pcl,  const int* __restrict__ cur_mask,
    const int*   __restrict__ cur_grid,
    int* __restrict__ head, float4* __restrict__ node)
{
    int gid = blockIdx.x * blockDim.x + threadIdx.x;
    if (gid >= NCLOUD * N_PTS) return;
    int c = gid / N_PTS;
    int n = gid - c * N_PTS;
    int t = c & 1;
    int b = c >> 1;
    const int*   msk = t ? cur_mask : prev_mask;
    const int*   grd = t ? cur_grid : prev_grid;
    const float* pcl = t ? cur_pcl  : prev_pcl;
    int e = b * N_PTS + n;
    if (!msk[e]) return;
    int p = grd[e];
    const float* q = pcl + (size_t)e * 3;
    int old = atomicExch(&head[c * P_CELLS + p], gid);
    node[gid] = make_float4(q[0], q[1], q[2], __int_as_float(old));
}

// ---------------------------------------------------------------------------
// Kernel 2: gather. One thread per (cloud c, cell p). Chain hop = ONE 16 B
// load. Feature loop uses wave-uniform scalar constants (s_load, 1 SGPR per
// v_fma operand slot — off the LDS/VALU-address path). Inactive lanes masked
// by a 0/1 multiplier so the loop runs once per wave-iteration, not per point.
// Output written exactly once, dense 256 B per wave-store.
// ---------------------------------------------------------------------------
__global__ __launch_bounds__(256) void gather_kernel(
    const int* __restrict__ head, const float4* __restrict__ node,
    const float* __restrict__ k,   // k0|k1|k2|k3, 64 each
    float* __restrict__ out)
{
    const int tid = threadIdx.x;
    const int c = blockIdx.y;                          // cloud 0..3
    const int p = blockIdx.x * blockDim.x + tid;       // cell 0..P-1

    float acc[64];
#pragma unroll
    for (int d = 0; d < 64; ++d) acc[d] = 0.f;

    int idx = head[c * P_CELLS + p];                   // coalesced 256 B/wave

    while (__ballot(idx >= 0)) {
        const bool act = (idx >= 0);
        // Predicated fat-node load: inactive lanes re-read node[0] harmlessly.
        float4 nd = node[act ? idx : 0];
        const float m = act ? 1.f : 0.f;
        const float x = nd.x, y = nd.y, z = nd.z;
        if (act) idx = __float_as_int(nd.w);
#pragma unroll
        for (int d = 0; d < 64; ++d) {
            float v = fmaf(x, k[d], fmaf(y, k[64 + d], fmaf(z, k[128 + d], k[192 + d])));
            acc[d] = fmaf(fmaxf(v, 0.f), m, acc[d]);
        }
    }

    float* op = out + (size_t)c * 64u * P_CELLS + p;
#pragma unroll
    for (int d = 0; d < 64; ++d)
        op[(size_t)d * P_CELLS] = acc[d];
}

// ---------------------------------------------------------------------------
extern "C" void kernel_launch(void* const* d_in, const int* in_sizes, int n_in,
                              void* d_out, int out_size, void* d_ws, size_t ws_size,
                              hipStream_t stream) {
    const float* prev_pcl  = (const float*)d_in[0];
    const int*   prev_mask = (const int*)  d_in[1];
    const int*   prev_grid = (const int*)  d_in[2];
    const float* cur_pcl   = (const float*)d_in[3];
    const int*   cur_mask  = (const int*)  d_in[4];
    const int*   cur_grid  = (const int*)  d_in[5];
    const float* W     = (const float*)d_in[6];
    const float* bvec  = (const float*)d_in[7];
    const float* gam   = (const float*)d_in[8];
    const float* bet   = (const float*)d_in[9];
    const float* mean  = (const float*)d_in[10];
    const float* var   = (const float*)d_in[11];
    float* out = (float*)d_out;

    float*  consts = (float*)d_ws;
    int*    head   = (int*)((char*)d_ws + WS_HEAD_OFF);
    float4* node   = (float4*)((char*)d_ws + WS_HEAD_OFF
                               + (size_t)NCLOUD * P_CELLS * sizeof(int));

    // Fused constants (64 threads) + head = -1.
    make_consts<<<1, 64, 0, stream>>>(W, bvec, gam, bet, mean, var, consts);
    hipMemsetAsync(head, 0xFF, (size_t)NCLOUD * P_CELLS * sizeof(int), stream);

    // Build fat-node chains: 400k point-tasks.
    build_lists<<<(NCLOUD * N_PTS + 255) / 256, 256, 0, stream>>>(
        prev_pcl, prev_mask, prev_grid, cur_pcl, cur_mask, cur_grid,
        head, node);

    // Gather: 4 clouds x 409600 cells, one thread each.
    dim3 ggrid(P_CELLS / 256, NCLOUD);
    gather_kernel<<<ggrid, 256, 0, stream>>>(head, node, consts, out);
}